// Round 1
// baseline (940.555 us; speedup 1.0000x reference)
//
#include <hip/hip_runtime.h>
#include <math.h>

// NoisyTokenChoiceRouter: N=16384 tokens, D=2048, E=64 experts, top-k=2.
// Outputs (concatenated fp32 in d_out):
//   [0, 2N)      top_k_values (normalized noisy gates, descending)
//   [2N, 4N)     top_k_indices (written as float(idx))
//   [4N]         aux_loss scalar
#define NTOK 16384
#define DDIM 2048
#define NEXP 64
#define TOK  8          // tokens per wave
#define NBUCKET 32      // hierarchical-atomic buckets for aux partial sums

__device__ __forceinline__ float wave_sum64(float v) {
  #pragma unroll
  for (int off = 32; off > 0; off >>= 1) v += __shfl_xor(v, off, 64);
  return v;
}

__device__ __forceinline__ float wave_max64(float v) {
  #pragma unroll
  for (int off = 32; off > 0; off >>= 1) v = fmaxf(v, __shfl_xor(v, off, 64));
  return v;
}

// max with lowest-index tie-break (matches jax.lax.top_k stability)
__device__ __forceinline__ void wave_argmax64(float &v, int &idx) {
  #pragma unroll
  for (int off = 32; off > 0; off >>= 1) {
    float ov = __shfl_xor(v, off, 64);
    int   oi = __shfl_xor(idx, off, 64);
    if (ov > v || (ov == v && oi < idx)) { v = ov; idx = oi; }
  }
}

__global__ __launch_bounds__(64) void router_main(
    const float* __restrict__ x, const float* __restrict__ W,
    const float* __restrict__ b, const float* __restrict__ noise,
    float* __restrict__ out, float* __restrict__ imp_part,
    float* __restrict__ load_part) {
  const int lane = threadIdx.x;                 // lane == expert index
  const int token0 = blockIdx.x * TOK;          // wave-uniform (blockIdx only)
  const float bias = b[lane];

  float acc[TOK];
  #pragma unroll
  for (int t = 0; t < TOK; ++t) acc[t] = 0.0f;

  const float* xr = x + (size_t)token0 * DDIM;

  // matmul: lane e accumulates logits for TOK tokens, column e of W.
  // W row (256B) coalesced per d; x loads are uniform -> scalar path.
  #pragma unroll 2
  for (int d = 0; d < DDIM; d += 4) {
    const float w0 = W[(size_t)(d + 0) * NEXP + lane];
    const float w1 = W[(size_t)(d + 1) * NEXP + lane];
    const float w2 = W[(size_t)(d + 2) * NEXP + lane];
    const float w3 = W[(size_t)(d + 3) * NEXP + lane];
    #pragma unroll
    for (int t = 0; t < TOK; ++t) {
      const float4 xv = *reinterpret_cast<const float4*>(xr + (size_t)t * DDIM + d);
      acc[t] = fmaf(xv.x, w0, acc[t]);
      acc[t] = fmaf(xv.y, w1, acc[t]);
      acc[t] = fmaf(xv.z, w2, acc[t]);
      acc[t] = fmaf(xv.w, w3, acc[t]);
    }
  }

  const float noise_std = 1.0f / (float)NEXP;
  const float inv_noise = (float)NEXP;
  const float inv_sqrt2 = 0.70710678118654752440f;

  float imp_acc = 0.0f, load_acc = 0.0f;

  for (int t = 0; t < TOK; ++t) {
    const int token = token0 + t;
    const float logit = acc[t] + bias;

    // clean softmax -> importance accumulation
    const float m = wave_max64(logit);
    const float ex = expf(logit - m);
    const float Z = wave_sum64(ex);
    imp_acc += ex / Z;

    // noisy logits
    const float noisy = fmaf(noise[(size_t)token * NEXP + lane], noise_std, logit);

    // top-2 (indices identical for gates_noisy since softmax is monotonic)
    float v1 = noisy; int i1 = lane;
    wave_argmax64(v1, i1);
    float masked = (lane == i1) ? -INFINITY : noisy;
    float v2 = masked; int i2 = lane;
    wave_argmax64(v2, i2);

    // noisy softmax denominator
    const float exn = expf(noisy - v1);
    const float Zn = wave_sum64(exn);
    const float g1 = 1.0f / Zn;              // exp(v1 - v1) / Zn
    const float g2 = expf(v2 - v1) / Zn;
    const float s = g1 + g2 + 1e-20f;

    if (lane == 0) {
      out[(size_t)token * 2 + 0] = g1 / s;
      out[(size_t)token * 2 + 1] = g2 / s;
      out[(size_t)NTOK * 2 + (size_t)token * 2 + 0] = (float)i1;
      out[(size_t)NTOK * 2 + (size_t)token * 2 + 1] = (float)i2;
    }

    // load loss: p = 1 - Phi((threshold - logit)/noise_std), threshold = v2
    const float z = (v2 - logit) * inv_noise;
    const float p = 1.0f - 0.5f * (1.0f + erff(z * inv_sqrt2));
    load_acc += p;
  }

  const int bucket = blockIdx.x & (NBUCKET - 1);
  atomicAdd(&imp_part[bucket * NEXP + lane], imp_acc);
  atomicAdd(&load_part[bucket * NEXP + lane], load_acc);
}

__global__ __launch_bounds__(64) void router_aux(
    const float* __restrict__ imp_part, const float* __restrict__ load_part,
    float* __restrict__ out) {
  const int lane = threadIdx.x;
  float imp = 0.0f, ld = 0.0f;
  #pragma unroll
  for (int k = 0; k < NBUCKET; ++k) {
    imp += imp_part[k * NEXP + lane];
    ld  += load_part[k * NEXP + lane];
  }
  ld *= 1.0f / (float)NTOK;   // p_mean

  // CV^2 with ddof=1, eps=1e-8 (matches reference formula shape)
  const float mean_i = wave_sum64(imp) * (1.0f / (float)NEXP);
  const float di = imp - mean_i;
  const float var_i = wave_sum64(di * di) * (1.0f / (float)(NEXP - 1));
  const float cv_i = sqrtf(var_i) / (mean_i + 1e-8f);

  const float mean_l = wave_sum64(ld) * (1.0f / (float)NEXP);
  const float dl = ld - mean_l;
  const float var_l = wave_sum64(dl * dl) * (1.0f / (float)(NEXP - 1));
  const float cv_l = sqrtf(var_l) / (mean_l + 1e-8f);

  if (lane == 0) out[(size_t)NTOK * 4] = 0.5f * (cv_i * cv_i + cv_l * cv_l);
}

extern "C" void kernel_launch(void* const* d_in, const int* in_sizes, int n_in,
                              void* d_out, int out_size, void* d_ws, size_t ws_size,
                              hipStream_t stream) {
  const float* x     = (const float*)d_in[0];
  const float* W     = (const float*)d_in[1];
  const float* b     = (const float*)d_in[2];
  const float* noise = (const float*)d_in[3];
  float* out = (float*)d_out;

  float* imp_part  = (float*)d_ws;                 // [NBUCKET][NEXP]
  float* load_part = imp_part + NBUCKET * NEXP;    // [NBUCKET][NEXP]

  hipMemsetAsync(d_ws, 0, 2 * NBUCKET * NEXP * sizeof(float), stream);
  router_main<<<NTOK / TOK, 64, 0, stream>>>(x, W, b, noise, out, imp_part, load_part);
  router_aux<<<1, 64, 0, stream>>>(imp_part, load_part, out);
}

// Round 3
// 527.735 us; speedup vs baseline: 1.7822x; 1.7822x over previous
//
#include <hip/hip_runtime.h>
#include <math.h>

// NoisyTokenChoiceRouter: N=16384 tokens, D=2048, E=64 experts, top-k=2.
// Outputs (concatenated fp32 in d_out):
//   [0, 2N)      top_k_values (normalized noisy gates, descending)
//   [2N, 4N)     top_k_indices (written as float(idx))
//   [4N]         aux_loss scalar
//
// R3 structure: INDEPENDENT waves (no LDS, no barriers, no cross-wave data).
// lane == expert. Each wave owns TOK=4 tokens over the FULL D, with the
// per-token fmaf chain byte-identical to round 1 (which validated at
// absmax 0.0 -- bitwise match incl. top-2 indices). Round 2's D-split
// changed summation order and flipped near-tie top-2 picks (index absmax
// 59 post-timing); do NOT reorder the accumulation chain.
// 4 waves/block x 1024 blocks = 4096 waves = 16 waves/CU (2x round 1).
#define NTOK 16384
#define DDIM 2048
#define NEXP 64
#define TOK  4            // tokens per wave
#define WPB  4            // independent waves per block
#define NBUCKET 32        // hierarchical-atomic buckets for aux partial sums

__device__ __forceinline__ float wave_sum64(float v) {
  #pragma unroll
  for (int off = 32; off > 0; off >>= 1) v += __shfl_xor(v, off, 64);
  return v;
}

__device__ __forceinline__ float wave_max64(float v) {
  #pragma unroll
  for (int off = 32; off > 0; off >>= 1) v = fmaxf(v, __shfl_xor(v, off, 64));
  return v;
}

// max with lowest-index tie-break (matches jax.lax.top_k stability)
__device__ __forceinline__ void wave_argmax64(float &v, int &idx) {
  #pragma unroll
  for (int off = 32; off > 0; off >>= 1) {
    float ov = __shfl_xor(v, off, 64);
    int   oi = __shfl_xor(idx, off, 64);
    if (ov > v || (ov == v && oi < idx)) { v = ov; idx = oi; }
  }
}

__global__ __launch_bounds__(256) void router_main(
    const float* __restrict__ x, const float* __restrict__ W,
    const float* __restrict__ b, const float* __restrict__ noise,
    float* __restrict__ out, float* __restrict__ imp_part,
    float* __restrict__ load_part) {
  const int lane = threadIdx.x & 63;              // lane == expert index
  const int wid  = threadIdx.x >> 6;              // independent wave id
  const int gwave = blockIdx.x * WPB + wid;
  const int token0 = gwave * TOK;                 // wave-uniform
  const float bias = b[lane];

  float acc[TOK];
  #pragma unroll
  for (int t = 0; t < TOK; ++t) acc[t] = 0.0f;

  const float* xr = x + (size_t)token0 * DDIM;

  // matmul: lane e accumulates logits for TOK tokens, column e of W.
  // W row (256B) coalesced per d (L2-hot). x loads wave-uniform -> scalar
  // path; unroll 4 gives 4 consecutive float4 per token (64B contiguous)
  // for wider merged s_loads / deeper MLP.
  // INVARIANT: per-token fmaf chain order == round 1 (bitwise-exact logits).
  #pragma unroll 4
  for (int d = 0; d < DDIM; d += 4) {
    const float w0 = W[(size_t)(d + 0) * NEXP + lane];
    const float w1 = W[(size_t)(d + 1) * NEXP + lane];
    const float w2 = W[(size_t)(d + 2) * NEXP + lane];
    const float w3 = W[(size_t)(d + 3) * NEXP + lane];
    #pragma unroll
    for (int t = 0; t < TOK; ++t) {
      const float4 xv = *reinterpret_cast<const float4*>(xr + (size_t)t * DDIM + d);
      acc[t] = fmaf(xv.x, w0, acc[t]);
      acc[t] = fmaf(xv.y, w1, acc[t]);
      acc[t] = fmaf(xv.z, w2, acc[t]);
      acc[t] = fmaf(xv.w, w3, acc[t]);
    }
  }

  const float noise_std = 1.0f / (float)NEXP;
  const float inv_noise = (float)NEXP;
  const float inv_sqrt2 = 0.70710678118654752440f;

  float imp_acc = 0.0f, load_acc = 0.0f;

  #pragma unroll
  for (int t = 0; t < TOK; ++t) {
    const int token = token0 + t;
    const float logit = acc[t] + bias;

    // clean softmax -> importance accumulation
    const float m = wave_max64(logit);
    const float ex = expf(logit - m);
    const float Z = wave_sum64(ex);
    imp_acc += ex / Z;

    // noisy logits
    const float noisy = fmaf(noise[(size_t)token * NEXP + lane], noise_std, logit);

    // top-2 (indices identical for gates_noisy: softmax is monotonic)
    float v1 = noisy; int i1 = lane;
    wave_argmax64(v1, i1);
    float masked = (lane == i1) ? -INFINITY : noisy;
    float v2 = masked; int i2 = lane;
    wave_argmax64(v2, i2);

    // noisy softmax
    const float exn = expf(noisy - v1);
    const float Zn = wave_sum64(exn);
    const float g1 = 1.0f / Zn;
    const float g2 = expf(v2 - v1) / Zn;
    const float s = g1 + g2 + 1e-20f;

    if (lane == 0) {
      out[(size_t)token * 2 + 0] = g1 / s;
      out[(size_t)token * 2 + 1] = g2 / s;
      out[(size_t)NTOK * 2 + (size_t)token * 2 + 0] = (float)i1;
      out[(size_t)NTOK * 2 + (size_t)token * 2 + 1] = (float)i2;
    }

    // load loss: p = 1 - Phi((threshold - logit)/noise_std), threshold = v2
    const float z = (v2 - logit) * inv_noise;
    const float p = 1.0f - 0.5f * (1.0f + erff(z * inv_sqrt2));
    load_acc += p;
  }

  const int bucket = gwave & (NBUCKET - 1);
  atomicAdd(&imp_part[bucket * NEXP + lane], imp_acc);
  atomicAdd(&load_part[bucket * NEXP + lane], load_acc);
}

__global__ __launch_bounds__(64) void router_aux(
    const float* __restrict__ imp_part, const float* __restrict__ load_part,
    float* __restrict__ out) {
  const int lane = threadIdx.x;
  float imp = 0.0f, ld = 0.0f;
  #pragma unroll
  for (int k = 0; k < NBUCKET; ++k) {
    imp += imp_part[k * NEXP + lane];
    ld  += load_part[k * NEXP + lane];
  }
  ld *= 1.0f / (float)NTOK;   // p_mean

  const float mean_i = wave_sum64(imp) * (1.0f / (float)NEXP);
  const float di = imp - mean_i;
  const float var_i = wave_sum64(di * di) * (1.0f / (float)(NEXP - 1));
  const float cv_i = sqrtf(var_i) / (mean_i + 1e-8f);

  const float mean_l = wave_sum64(ld) * (1.0f / (float)NEXP);
  const float dl = ld - mean_l;
  const float var_l = wave_sum64(dl * dl) * (1.0f / (float)(NEXP - 1));
  const float cv_l = sqrtf(var_l) / (mean_l + 1e-8f);

  if (lane == 0) out[(size_t)NTOK * 4] = 0.5f * (cv_i * cv_i + cv_l * cv_l);
}

extern "C" void kernel_launch(void* const* d_in, const int* in_sizes, int n_in,
                              void* d_out, int out_size, void* d_ws, size_t ws_size,
                              hipStream_t stream) {
  const float* x     = (const float*)d_in[0];
  const float* W     = (const float*)d_in[1];
  const float* b     = (const float*)d_in[2];
  const float* noise = (const float*)d_in[3];
  float* out = (float*)d_out;

  float* imp_part  = (float*)d_ws;                 // [NBUCKET][NEXP]
  float* load_part = imp_part + NBUCKET * NEXP;    // [NBUCKET][NEXP]

  hipMemsetAsync(d_ws, 0, 2 * NBUCKET * NEXP * sizeof(float), stream);
  router_main<<<NTOK / (TOK * WPB), 256, 0, stream>>>(x, W, b, noise, out,
                                                      imp_part, load_part);
  router_aux<<<1, 64, 0, stream>>>(imp_part, load_part, out);
}